// Round 7
// baseline (342.931 us; speedup 1.0000x reference)
//
#include <hip/hip_runtime.h>
#include <math.h>

// DownConvFace: 3 stages of {mesh_conv -> BN(global stats) -> (+res) -> LeakyReLU(0.2)}
// B=4, F=50000, Cin=32/64/64, O=64, fp32 in/out.
//
// R7: LDS-free conv. Contraction reordered feature-major (k' = kk*CIN + c) so each
// MFMA B-fragment = 8 contiguous channels of one derived feature of one face,
// built in registers straight from the four 16-B gathers (lane (quad,l15) owns
// face l15's channel-chunk quad; 4 quads cover all channels; no redundancy).
// W pre-packed to matching k' order. Removes G-LDS (33.8KB->1KB), both barriers
// on the load->MFMA path, and all bank conflicts. Stats via shfl_xor over l15.

typedef __attribute__((ext_vector_type(8))) short short8;
typedef __attribute__((ext_vector_type(8))) unsigned short ushort8_t;
typedef __attribute__((ext_vector_type(4))) float f32x4;

union v8cast { ushort8_t u; short8 s; };

__device__ inline unsigned short f2bf(float v) {
    union { float f; unsigned u; } x; x.f = v;
    unsigned r = x.u + 0x7fffu + ((x.u >> 16) & 1u);   // RNE
    return (unsigned short)(r >> 16);
}
__device__ inline float bf2f(unsigned short u) {
    union { unsigned u; float f; } x; x.u = ((unsigned)u) << 16; return x.f;
}

// fe [B][32][F] fp32 -> fe_t [B][F][32] bf16. grid (ceil(F/64), B), block 256.
__global__ void transpose_fe_kernel(const float* __restrict__ fe,
                                    unsigned short* __restrict__ o, int F)
{
    __shared__ float tile[64 * 33];
    const int b = blockIdx.y;
    const int f0 = blockIdx.x * 64;
    const int t = threadIdx.x;
    const int lane = t & 63;
    const int w = t >> 6;
    const int f = f0 + lane;
    if (f < F) {
#pragma unroll
        for (int i = 0; i < 8; ++i) {
            const int c = w * 8 + i;
            tile[lane * 33 + c] = fe[((size_t)b * 32 + c) * F + f];
        }
    }
    __syncthreads();
    const int j = t >> 2, s = t & 3;
    const int fj = f0 + j;
    if (fj < F) {
        ushort8_t v;
#pragma unroll
        for (int i = 0; i < 8; ++i) v[i] = f2bf(tile[j * 33 + s * 8 + i]);
        *(ushort8_t*)(o + ((size_t)b * F + fj) * 32 + s * 8) = v;
    }
}

// Pack weights fp32->bf16 with feature-major K order: wp[o][kk*CIN + c] = w[o][c][kk].
__global__ void pack_weights_kernel(const float* __restrict__ w1,
                                    const float* __restrict__ w2a,
                                    const float* __restrict__ w2b,
                                    unsigned short* __restrict__ w1p,
                                    unsigned short* __restrict__ w2ap,
                                    unsigned short* __restrict__ w2bp)
{
    const int i = blockIdx.x * blockDim.x + threadIdx.x;
    if (i < 64 * 128) {
        const int o = i >> 7, r = i & 127, kk = r >> 5, c = r & 31;
        w1p[i] = f2bf(w1[(o * 32 + c) * 4 + kk]);
    }
    if (i < 64 * 256) {
        const int o = i >> 8, r = i & 255, kk = r >> 6, c = r & 63;
        w2ap[i] = f2bf(w2a[(o * 64 + c) * 4 + kk]);
        w2bp[i] = f2bf(w2b[(o * 64 + c) * 4 + kk]);
    }
}

// LDS-free fused mesh-conv GEMM + BN-stats. Block 256 (4 waves); wave wv handles
// faces f0 + wv*16 + [0,16); lane (quad q, l15) owns face l15's channel chunks.
// grid = (ceil(F/64), B). Y out bf16 [B*F][64]; stats partials pS/pQ [64][nb].
template <int CIN>
__launch_bounds__(256, 5)
__global__ void conv_mfma_kernel(const unsigned short* __restrict__ x,  // [B][F][CIN] bf16
                                 const int*   __restrict__ gidx,        // [B][F][3]
                                 const unsigned short* __restrict__ wp, // [64][K] bf16, k'=kk*CIN+c
                                 const float* __restrict__ bias,        // [64]
                                 unsigned short* __restrict__ y,        // [B*F][64] bf16
                                 float* __restrict__ pS,                // [64][nb]
                                 float* __restrict__ pQ,                // [64][nb]
                                 int nb, int F)
{
    constexpr int K   = 4 * CIN;
    constexpr int NCH = CIN / 32;            // channel chunks per pointer per lane
    __shared__ float redS[256], redQ[256];

    const int b  = blockIdx.y;
    const int f0 = blockIdx.x * 64;
    const int t  = threadIdx.x;
    const int lane = t & 63, wv = t >> 6;
    const int l15 = lane & 15, q = lane >> 4;

    const int f = f0 + wv * 16 + l15;
    const bool valid = f < F;
    const int fi = valid ? f : 0;

    const unsigned short* xb = x + (size_t)b * F * CIN;
    const int* gp = gidx + ((size_t)b * F + fi) * 3;
    const int g0 = gp[0], g1 = gp[1], g2 = gp[2];
    const unsigned short* pc = xb + (size_t)fi * CIN;
    const unsigned short* p0 = xb + (size_t)g0 * CIN;
    const unsigned short* p1 = xb + (size_t)g1 * CIN;
    const unsigned short* p2 = xb + (size_t)g2 * CIN;

    // ---- gather: 4*NCH independent 16-B loads, all issued up front ----
    ushort8_t vc[NCH], v0[NCH], v1[NCH], v2[NCH];
#pragma unroll
    for (int h = 0; h < NCH; ++h) {
        const int c0 = h * 32 + q * 8;
        vc[h] = *(const ushort8_t*)(pc + c0);
        v0[h] = *(const ushort8_t*)(p0 + c0);
        v1[h] = *(const ushort8_t*)(p1 + c0);
        v2[h] = *(const ushort8_t*)(p2 + c0);
    }

    // ---- feature build in registers: d[h][t], t = {ctr,sum,absdiff,max} ----
    ushort8_t d[NCH][4];
#pragma unroll
    for (int h = 0; h < NCH; ++h) {
        d[h][0] = vc[h];                      // center = raw loaded vector
        ushort8_t ds_, dd_, dm_;
#pragma unroll
        for (int e = 0; e < 8; ++e) {
            const float a  = bf2f(v0[h][e]);
            const float bb = bf2f(v1[h][e]);
            const float cc = bf2f(v2[h][e]);
            ds_[e] = f2bf(a + bb + cc);
            dd_[e] = f2bf(fabsf(a - bb) + fabsf(bb - cc) + fabsf(cc - a));
            dm_[e] = f2bf(fmaxf(a, fmaxf(bb, cc)));
        }
        d[h][1] = ds_; d[h][2] = dd_; d[h][3] = dm_;
    }
    if (!valid) {
        const ushort8_t z = {0, 0, 0, 0, 0, 0, 0, 0};
#pragma unroll
        for (int h = 0; h < NCH; ++h)
#pragma unroll
            for (int tt = 0; tt < 4; ++tt) d[h][tt] = z;
    }

    // ---- MFMA: kstep ks needs chunk h = ks%NCH, type t = ks/NCH ----
    f32x4 acc[4];
#pragma unroll
    for (int mt = 0; mt < 4; ++mt) acc[mt] = (f32x4){0.f, 0.f, 0.f, 0.f};

#pragma unroll
    for (int ks = 0; ks < K / 32; ++ks) {
        v8cast bc; bc.u = d[ks % NCH][ks / NCH];
        const short8 bfr = bc.s;
#pragma unroll
        for (int mt = 0; mt < 4; ++mt) {
            const short8 afr =
                *(const short8*)(wp + (size_t)(mt * 16 + l15) * K + ks * 32 + q * 8);
            acc[mt] = __builtin_amdgcn_mfma_f32_16x16x32_bf16(afr, bfr, acc[mt], 0, 0, 0);
        }
    }

    // ---- epilogue: bias, Y bf16 store, stats via shfl_xor over l15 ----
    float s16[4][4], q16[4][4];
#pragma unroll
    for (int mt = 0; mt < 4; ++mt) {
        const f32x4 b4 = *(const f32x4*)(bias + mt * 16 + q * 4);
        const f32x4 v = acc[mt] + b4;
        if (valid) {
            ushort4 u;
            u.x = f2bf(v[0]); u.y = f2bf(v[1]); u.z = f2bf(v[2]); u.w = f2bf(v[3]);
            *(ushort4*)(y + ((size_t)b * F + f) * 64 + mt * 16 + q * 4) = u;
        }
#pragma unroll
        for (int r = 0; r < 4; ++r) {
            const float vv = valid ? v[r] : 0.f;
            s16[mt][r] = vv;
            q16[mt][r] = vv * vv;
        }
    }
#pragma unroll
    for (int m_ = 1; m_ < 16; m_ <<= 1) {
#pragma unroll
        for (int mt = 0; mt < 4; ++mt)
#pragma unroll
            for (int r = 0; r < 4; ++r) {
                s16[mt][r] += __shfl_xor(s16[mt][r], m_);
                q16[mt][r] += __shfl_xor(q16[mt][r], m_);
            }
    }
    if (l15 == 0) {
#pragma unroll
        for (int mt = 0; mt < 4; ++mt)
#pragma unroll
            for (int r = 0; r < 4; ++r) {
                redS[wv * 64 + mt * 16 + q * 4 + r] = s16[mt][r];
                redQ[wv * 64 + mt * 16 + q * 4 + r] = q16[mt][r];
            }
    }
    __syncthreads();
    if (t < 64) {
        const float S = redS[t] + redS[64 + t] + redS[128 + t] + redS[192 + t];
        const float Q = redQ[t] + redQ[64 + t] + redQ[128 + t] + redQ[192 + t];
        const int blk = blockIdx.y * gridDim.x + blockIdx.x;
        pS[(size_t)t * nb + blk] = S;     // channel-major: coalesced finalize reads
        pQ[(size_t)t * nb + blk] = Q;
    }
}

// grid 64 (one block per channel), 256 threads. Contiguous reads of pS/pQ[o][0..nb).
__global__ void finalize_kernel(const float* __restrict__ pS, const float* __restrict__ pQ,
                                int nb, float invN,
                                const float* __restrict__ gamma,
                                const float* __restrict__ beta,
                                float* __restrict__ mr)
{
    __shared__ float rs_[256], rq_[256];
    const int o = blockIdx.x, t = threadIdx.x;
    float S = 0.f, Q = 0.f;
    for (int j = t; j < nb; j += 256) {
        S += pS[(size_t)o * nb + j];
        Q += pQ[(size_t)o * nb + j];
    }
    rs_[t] = S; rq_[t] = Q;
    __syncthreads();
#pragma unroll
    for (int s = 128; s > 0; s >>= 1) {
        if (t < s) { rs_[t] += rs_[t + s]; rq_[t] += rq_[t + s]; }
        __syncthreads();
    }
    if (t == 0) {
        const float mu  = rs_[0] * invN;
        const float var = rq_[0] * invN - mu * mu;
        const float rsg = rsqrtf(var + 1e-5f);
        const float sc  = gamma[o] * rsg;
        mr[o]      = sc;
        mr[64 + o] = fmaf(-sc, mu, beta[o]);
    }
}

// BN+res+lrelu, face-major bf16 -> bf16. tid over M*64/4 groups.
__global__ void norm_kernel(const unsigned short* __restrict__ y,   // [M][64] bf16
                            const unsigned short* __restrict__ res, // [M][64] bf16 or null
                            const float* __restrict__ mr,
                            unsigned short* __restrict__ out,       // [M][64] bf16
                            int N4)
{
    const int tid = blockIdx.x * blockDim.x + threadIdx.x;
    if (tid >= N4) return;
    const int c0 = (tid & 15) * 4;
    const ushort4 yv = *(const ushort4*)(y + (size_t)tid * 4);
    const f32x4 sc = *(const f32x4*)(mr + c0);
    const f32x4 sh = *(const f32x4*)(mr + 64 + c0);
    float r[4] = {fmaf(bf2f(yv.x), sc[0], sh[0]), fmaf(bf2f(yv.y), sc[1], sh[1]),
                  fmaf(bf2f(yv.z), sc[2], sh[2]), fmaf(bf2f(yv.w), sc[3], sh[3])};
    if (res) {
        const ushort4 u = *(const ushort4*)(res + (size_t)tid * 4);
        r[0] += bf2f(u.x); r[1] += bf2f(u.y); r[2] += bf2f(u.z); r[3] += bf2f(u.w);
    }
    ushort4 o;
    o.x = f2bf(r[0] >= 0.f ? r[0] : 0.2f * r[0]);
    o.y = f2bf(r[1] >= 0.f ? r[1] : 0.2f * r[1]);
    o.z = f2bf(r[2] >= 0.f ? r[2] : 0.2f * r[2]);
    o.w = f2bf(r[3] >= 0.f ? r[3] : 0.2f * r[3]);
    *(ushort4*)(out + (size_t)tid * 4) = o;
}

// Final BN+res+lrelu fused with transpose [B*F][64] -> [B][64][F] fp32 (d_out).
__global__ void norm_transpose_kernel(const unsigned short* __restrict__ y,   // bf16
                                      const unsigned short* __restrict__ res, // bf16
                                      const float* __restrict__ mr,
                                      float* __restrict__ out, int F)
{
    __shared__ float tile[64 * 65];
    const int b = blockIdx.y, f0 = blockIdx.x * 64, t = threadIdx.x;
    const int j = t >> 2, s = t & 3;
    const int f = f0 + j;
    if (f < F) {
        const size_t row = ((size_t)b * F + f) * 64;
#pragma unroll
        for (int i = 0; i < 4; ++i) {
            const int c0 = (i * 4 + s) * 4;
            const ushort4 yv = *(const ushort4*)(y + row + c0);
            const f32x4 sc = *(const f32x4*)(mr + c0);
            const f32x4 sh = *(const f32x4*)(mr + 64 + c0);
            const ushort4 u = *(const ushort4*)(res + row + c0);
            const float yf[4] = {bf2f(yv.x), bf2f(yv.y), bf2f(yv.z), bf2f(yv.w)};
            const float rv[4] = {bf2f(u.x), bf2f(u.y), bf2f(u.z), bf2f(u.w)};
#pragma unroll
            for (int qq = 0; qq < 4; ++qq) {
                float vv = fmaf(yf[qq], sc[qq], sh[qq]) + rv[qq];
                vv = vv >= 0.f ? vv : 0.2f * vv;
                tile[(c0 + qq) * 65 + j] = vv;
            }
        }
    }
    __syncthreads();
    const int o = t >> 2;
    float* ob = out + ((size_t)b * 64 + o) * F + f0;
#pragma unroll
    for (int i = 0; i < 4; ++i) {
        const int fs = (i * 4 + s) * 4;
        if (f0 + fs < F) {
            f32x4 v;
#pragma unroll
            for (int qq = 0; qq < 4; ++qq) v[qq] = tile[o * 65 + fs + qq];
            *(f32x4*)(ob + fs) = v;
        }
    }
}

extern "C" void kernel_launch(void* const* d_in, const int* in_sizes, int n_in,
                              void* d_out, int out_size, void* d_ws, size_t ws_size,
                              hipStream_t stream)
{
    const float* fe  = (const float*)d_in[0];
    const int*   gm  = (const int*)d_in[1];
    const float* w1  = (const float*)d_in[2];
    const float* b1  = (const float*)d_in[3];
    const float* w2a = (const float*)d_in[4];
    const float* b2a = (const float*)d_in[5];
    const float* w2b = (const float*)d_in[6];
    const float* b2b = (const float*)d_in[7];
    const float* g0  = (const float*)d_in[8];
    const float* be0 = (const float*)d_in[9];
    const float* g1  = (const float*)d_in[10];
    const float* be1 = (const float*)d_in[11];
    const float* g2  = (const float*)d_in[12];
    const float* be2 = (const float*)d_in[13];

    const int B = 4, O = 64;
    const int F = in_sizes[0] / (B * 32);
    const int M = B * F;
    const float invN = 1.0f / (float)M;
    const int nbx = (F + 63) / 64;
    const int nb  = nbx * B;

    // Workspace: bufY bf16 [M][64] + xbuf bf16 [M][64] + partials + weights.
    unsigned short* bufY = (unsigned short*)d_ws;
    unsigned short* xbuf = bufY + (size_t)M * O;
    float* pS   = (float*)(xbuf + (size_t)M * O);       // [64][nb]
    float* pQ   = pS + (size_t)64 * nb;                 // [64][nb]
    float* mr   = pQ + (size_t)64 * nb;                 // [2][64]
    unsigned short* w1p  = (unsigned short*)(mr + 128); // [64][128]
    unsigned short* w2ap = w1p + 64 * 128;              // [64][256]
    unsigned short* w2bp = w2ap + 64 * 256;             // [64][256]
    unsigned short* fe_t = (unsigned short*)d_out;      // [B][F][32] bf16, dead after conv1

    dim3 blk(256);
    dim3 cgrid(nbx, B);
    const int N4 = M * 16;
    dim3 ngrid((N4 + 255) / 256);

    transpose_fe_kernel<<<cgrid, blk, 0, stream>>>(fe, fe_t, F);
    pack_weights_kernel<<<64, 256, 0, stream>>>(w1, w2a, w2b, w1p, w2ap, w2bp);

    // ---- Stage 1 ----
    conv_mfma_kernel<32><<<cgrid, blk, 0, stream>>>(fe_t, gm, w1p, b1, bufY, pS, pQ, nb, F);
    finalize_kernel<<<64, 256, 0, stream>>>(pS, pQ, nb, invN, g0, be0, mr);
    norm_kernel<<<ngrid, blk, 0, stream>>>(bufY, nullptr, mr, xbuf, N4);

    // ---- Stage 2 ----
    conv_mfma_kernel<64><<<cgrid, blk, 0, stream>>>(xbuf, gm, w2ap, b2a, bufY, pS, pQ, nb, F);
    finalize_kernel<<<64, 256, 0, stream>>>(pS, pQ, nb, invN, g1, be1, mr);
    norm_kernel<<<ngrid, blk, 0, stream>>>(bufY, xbuf, mr, xbuf, N4);

    // ---- Stage 3 ----
    conv_mfma_kernel<64><<<cgrid, blk, 0, stream>>>(xbuf, gm, w2bp, b2b, bufY, pS, pQ, nb, F);
    finalize_kernel<<<64, 256, 0, stream>>>(pS, pQ, nb, invN, g2, be2, mr);
    norm_transpose_kernel<<<cgrid, blk, 0, stream>>>(bufY, xbuf, mr, (float*)d_out, F);
}